// Round 1
// baseline (166.875 us; speedup 1.0000x reference)
//
#include <hip/hip_runtime.h>
#include <stdint.h>

#define BATCH 512
#define D_IN 1024
#define D_OUT 1024
#define BITSZ 128
#define N_STEPS (D_IN - 2)  // 1022

// JAX >= 0.4.36 defaults jax_threefry_partitionable=True. If this round fails
// with absmax ~0.3-0.9 (statistically-independent randomness), flip to false.
constexpr bool PARTITIONABLE = true;

// Flattened-array halves for the legacy (non-partitionable) counter layout.
#define HALF_X ((uint32_t)(BATCH * D_IN * BITSZ) / 2u)    // 33554432
#define HALF_W ((uint32_t)(D_IN * D_OUT * BITSZ) / 2u)    // 67108864
#define HALF_C ((uint32_t)(N_STEPS * BATCH * BITSZ) / 2u) // 33488896

__host__ __device__ __forceinline__ uint32_t rotl32(uint32_t x, uint32_t d) {
  return (x << d) | (x >> (32u - d));
}

// Threefry-2x32, 20 rounds, exactly as jax/_src/prng.py lowering.
__host__ __device__ __forceinline__ void threefry2x32(uint32_t k0, uint32_t k1,
                                                      uint32_t& x0, uint32_t& x1) {
  const uint32_t k2 = k0 ^ k1 ^ 0x1BD11BDAu;
  x0 += k0; x1 += k1;
#define TFR(r) { x0 += x1; x1 = rotl32(x1, (r)); x1 ^= x0; }
  TFR(13) TFR(15) TFR(26) TFR(6)
  x0 += k1; x1 += k2 + 1u;
  TFR(17) TFR(29) TFR(16) TFR(24)
  x0 += k2; x1 += k0 + 2u;
  TFR(13) TFR(15) TFR(26) TFR(6)
  x0 += k0; x1 += k1 + 3u;
  TFR(17) TFR(29) TFR(16) TFR(24)
  x0 += k1; x1 += k2 + 4u;
  TFR(13) TFR(15) TFR(26) TFR(6)
  x0 += k2; x1 += k0 + 5u;
#undef TFR
}

// random_bits for element n of a flat array of even total size 2*half, <2^32.
__device__ __forceinline__ uint32_t rbits(uint32_t k0, uint32_t k1,
                                          uint32_t n, uint32_t half) {
  if (PARTITIONABLE) {
    // counts = (hi, lo) of 64-bit linear index; sizes < 2^32 so hi = 0.
    uint32_t x0 = 0u, x1 = n;
    threefry2x32(k0, k1, x0, x1);
    return x0 ^ x1;  // 32-bit fold
  } else {
    const bool lo = n < half;
    uint32_t x0 = lo ? n : (n - half);
    uint32_t x1 = lo ? (n + half) : n;
    threefry2x32(k0, k1, x0, x1);
    return lo ? x0 : x1;
  }
}

// jax.random.uniform float32 path: (bits>>9)|0x3f800000 bitcast - 1.0f
__device__ __forceinline__ float runif(uint32_t k0, uint32_t k1,
                                       uint32_t n, uint32_t half) {
  const uint32_t b = rbits(k0, k1, n, half);
  return __uint_as_float((b >> 9) | 0x3f800000u) - 1.0f;
}

// Kernel 1: per (b,t) compute idx = max row with coin==False (scan from the
// top; geometric, ~2 iters expected), then chosen_x bit. v = xbit ? idx : -1.
__global__ void __launch_bounds__(256) k_idx(const float* __restrict__ x,
                                             int* __restrict__ v,
                                             uint32_t ck0, uint32_t ck1,
                                             uint32_t xk0, uint32_t xk1) {
  const int tid = blockIdx.x * blockDim.x + threadIdx.x;  // 0..65535
  const int b = tid >> 7;
  const int t = tid & 127;

  int idx = 0;
  for (int s = N_STEPS - 1; s >= 0; --s) {
    // coins linear index: s*(BATCH*BITSZ) + b*BITSZ + t == (s<<16) + tid
    const uint32_t n = ((uint32_t)s << 16) + (uint32_t)tid;
    const float u = runif(ck0, ck1, n, HALF_C);
    if (u > 0.5f) { idx = s + 1; break; }  // coin False -> row s+1 survives
  }

  // x_bits linear index: b*(D_IN*BITSZ) + idx*BITSZ + t
  const uint32_t nx = ((uint32_t)b << 17) + ((uint32_t)idx << 7) + (uint32_t)t;
  const float ux = runif(xk0, xk1, nx, HALF_X);
  const int xb = (ux <= x[b * D_IN + idx]) ? 1 : 0;
  v[tid] = xb ? idx : -1;
}

// Kernel 2: one thread per (b,d). out[b,d] = (1/128) * sum_t wbit[v[t], d, t]
// over t with xbit set. The i<0 skip and i value are block-uniform.
__global__ void __launch_bounds__(1024) k_acc(const float* __restrict__ w,
                                              const int* __restrict__ v,
                                              float* __restrict__ out,
                                              uint32_t wk0, uint32_t wk1) {
  const int b = blockIdx.x;
  const int d = threadIdx.x;

  __shared__ int sv[BITSZ];
  if (threadIdx.x < BITSZ) sv[threadIdx.x] = v[b * BITSZ + threadIdx.x];
  __syncthreads();

  int acc = 0;
  for (int t = 0; t < BITSZ; ++t) {
    const int i = sv[t];
    if (i < 0) continue;  // xbit==0: term is 0 for every d (uniform branch)
    const float wv = w[i * D_OUT + d];
    // w_bits linear index: i*(D_OUT*BITSZ) + d*BITSZ + t
    const uint32_t n = (uint32_t)i * (uint32_t)(D_OUT * BITSZ)
                     + ((uint32_t)d << 7) + (uint32_t)t;
    const float u = runif(wk0, wk1, n, HALF_W);
    acc += (u <= wv) ? 1 : 0;
  }
  out[b * D_OUT + d] = (float)acc * (1.0f / (float)BITSZ);
}

struct TFKeys { uint32_t xk0, xk1, wk0, wk1, ck0, ck1; };

static TFKeys derive_keys() {
  TFKeys K;
  if (PARTITIONABLE) {
    // split: key_i = both output words of E_{(0,42)}(0, i)
    uint32_t a0 = 0, a1 = 0; threefry2x32(0u, 42u, a0, a1); K.xk0 = a0; K.xk1 = a1;
    uint32_t b0 = 0, b1 = 1; threefry2x32(0u, 42u, b0, b1); K.wk0 = b0; K.wk1 = b1;
    uint32_t c0 = 0, c1 = 2; threefry2x32(0u, 42u, c0, c1); K.ck0 = c0; K.ck1 = c1;
  } else {
    // legacy split: counts [0..5] -> pairs (0,3),(1,4),(2,5); out = concat(w0s, w1s)
    uint32_t p0 = 0, p1 = 3; threefry2x32(0u, 42u, p0, p1);
    uint32_t q0 = 1, q1 = 4; threefry2x32(0u, 42u, q0, q1);
    uint32_t r0 = 2, r1 = 5; threefry2x32(0u, 42u, r0, r1);
    K.xk0 = p0; K.xk1 = q0;   // (out[0], out[1])
    K.wk0 = r0; K.wk1 = p1;   // (out[2], out[3])
    K.ck0 = q1; K.ck1 = r1;   // (out[4], out[5])
  }
  return K;
}

extern "C" void kernel_launch(void* const* d_in, const int* in_sizes, int n_in,
                              void* d_out, int out_size, void* d_ws, size_t ws_size,
                              hipStream_t stream) {
  const float* x = (const float*)d_in[0];
  const float* w = (const float*)d_in[1];
  // Defensive: x is 512*1024=524288 elems, w is 1024*1024=1048576.
  if (n_in >= 2 && in_sizes[0] == D_IN * D_OUT && in_sizes[1] == BATCH * D_IN) {
    const float* tmp = x; x = w; w = tmp;
  }
  float* out = (float*)d_out;
  int* v = (int*)d_ws;  // 65536 ints = 256 KB scratch

  const TFKeys K = derive_keys();

  hipLaunchKernelGGL(k_idx, dim3((BATCH * BITSZ) / 256), dim3(256), 0, stream,
                     x, v, K.ck0, K.ck1, K.xk0, K.xk1);
  hipLaunchKernelGGL(k_acc, dim3(BATCH), dim3(D_OUT), 0, stream,
                     w, v, out, K.wk0, K.wk1);
}

// Round 2
// 39.691 us; speedup vs baseline: 4.2044x; 4.2044x over previous
//
#include <hip/hip_runtime.h>
#include <stdint.h>

#define BATCH 512
#define D_IN 1024
#define D_OUT 1024
#define BITSZ 128
#define N_STEPS (D_IN - 2)  // 1022

// Table covers idx in [IBASE, 1024). P(any idx < IBASE) ~ 65536 * 2^-64 ~ 4e-15;
// a direct-cipher fallback in k_acc keeps correctness for the impossible case.
#define IBASE 960
#define ICAP 64  // rows per t column

// ws layout
#define WS_V_OFF 0u
#define WS_V_BYTES (BATCH * BITSZ * 4u)                 // 262144
#define WS_MASK_OFF (WS_V_OFF + WS_V_BYTES)             // 262144
#define WS_MASK_BYTES (BITSZ * 2u * 4u)                 // 1024
#define WS_TAB_OFF (WS_MASK_OFF + WS_MASK_BYTES)        // 263168
#define WS_TAB_BYTES (BITSZ * ICAP * 32u * 4u)          // 1048576
#define WS_NEEDED (WS_TAB_OFF + WS_TAB_BYTES)           // 1311744

__host__ __device__ __forceinline__ uint32_t rotl32(uint32_t x, uint32_t d) {
  return (x << d) | (x >> (32u - d));
}

// Threefry-2x32, 20 rounds, exactly as jax/_src/prng.py lowering.
__host__ __device__ __forceinline__ void threefry2x32(uint32_t k0, uint32_t k1,
                                                      uint32_t& x0, uint32_t& x1) {
  const uint32_t k2 = k0 ^ k1 ^ 0x1BD11BDAu;
  x0 += k0; x1 += k1;
#define TFR(r) { x0 += x1; x1 = rotl32(x1, (r)); x1 ^= x0; }
  TFR(13) TFR(15) TFR(26) TFR(6)
  x0 += k1; x1 += k2 + 1u;
  TFR(17) TFR(29) TFR(16) TFR(24)
  x0 += k2; x1 += k0 + 2u;
  TFR(13) TFR(15) TFR(26) TFR(6)
  x0 += k0; x1 += k1 + 3u;
  TFR(17) TFR(29) TFR(16) TFR(24)
  x0 += k1; x1 += k2 + 4u;
  TFR(13) TFR(15) TFR(26) TFR(6)
  x0 += k2; x1 += k0 + 5u;
#undef TFR
}

// jax_threefry_partitionable random_bits -> uniform [0,1): counts=(0,n), fold, mantissa trick.
__device__ __forceinline__ float runif(uint32_t k0, uint32_t k1, uint32_t n) {
  uint32_t x0 = 0u, x1 = n;
  threefry2x32(k0, k1, x0, x1);
  const uint32_t b = x0 ^ x1;
  return __uint_as_float((b >> 9) | 0x3f800000u) - 1.0f;
}

// Kernel 1: per (b,t): idx = max row with coin False (scan from top, geometric),
// chosen_x bit; v = xbit ? idx : -1. Also set presence mask[t] for table rows.
__global__ void __launch_bounds__(256) k_idx(const float* __restrict__ x,
                                             int* __restrict__ v,
                                             uint32_t* __restrict__ mask,
                                             uint32_t ck0, uint32_t ck1,
                                             uint32_t xk0, uint32_t xk1,
                                             int use_tab) {
  const int tid = blockIdx.x * blockDim.x + threadIdx.x;  // 0..65535
  const int b = tid >> 7;
  const int t = tid & 127;

  int idx = 0;
  for (int s = N_STEPS - 1; s >= 0; --s) {
    // coins linear index: s*(BATCH*BITSZ) + b*BITSZ + t == (s<<16) + tid
    const float u = runif(ck0, ck1, ((uint32_t)s << 16) + (uint32_t)tid);
    if (u > 0.5f) { idx = s + 1; break; }
  }

  // x_bits linear index: b*(D_IN*BITSZ) + idx*BITSZ + t
  const float ux = runif(xk0, xk1, ((uint32_t)b << 17) + ((uint32_t)idx << 7) + (uint32_t)t);
  const int xb = (ux <= x[b * D_IN + idx]) ? 1 : 0;
  v[tid] = xb ? idx : -1;

  if (xb && use_tab && idx >= IBASE) {
    const int bp = idx - IBASE;
    atomicOr(&mask[t * 2 + (bp >> 5)], 1u << (bp & 31));
  }
}

// Kernel 2: build 1024-bit row wbit[i, :, t] for each present (i,t).
// block = (j=i-IBASE, t), 256 threads, 4 d's per thread, ballot-packed.
__global__ void __launch_bounds__(256) k_tab(const float* __restrict__ w,
                                             const uint32_t* __restrict__ mask,
                                             uint32_t* __restrict__ tab,
                                             uint32_t wk0, uint32_t wk1) {
  const int j = blockIdx.x;   // 0..63
  const int t = blockIdx.y;   // 0..127
  if (!((mask[t * 2 + (j >> 5)] >> (j & 31)) & 1u)) return;
  const int i = IBASE + j;
  const int lane = threadIdx.x & 63;
  const int wv = threadIdx.x >> 6;  // wave 0..3
  uint32_t* row = tab + (((t << 6) + j) << 5);
  const float* wrow = w + i * D_OUT;
#pragma unroll
  for (int k = 0; k < 4; ++k) {
    const int d = k * 256 + wv * 64 + lane;
    // w_bits linear index: i*(D_OUT*BITSZ) + d*BITSZ + t
    const float u = runif(wk0, wk1, ((uint32_t)i << 17) + ((uint32_t)d << 7) + (uint32_t)t);
    const unsigned long long mb = __ballot(u <= wrow[d]);
    const int wbase = (k * 256 + wv * 64) >> 5;
    if (lane == 0)  row[wbase]     = (uint32_t)mb;
    if (lane == 32) row[wbase + 1] = (uint32_t)(mb >> 32);
  }
}

// Kernel 3: per block b: compact active (t,idx) pairs, stage their packed rows
// into LDS, accumulate bits per d. out[b,d] = acc/128.
__global__ void __launch_bounds__(1024) k_acc(const float* __restrict__ w,
                                              const int* __restrict__ v,
                                              const uint32_t* __restrict__ tab,
                                              float* __restrict__ out,
                                              uint32_t wk0, uint32_t wk1,
                                              int use_tab) {
  const int b = blockIdx.x;
  const int tid = threadIdx.x;  // == d

  __shared__ uint32_t s_tab[BITSZ * 32];  // 16 KB
  __shared__ int s_list[BITSZ];
  __shared__ int s_wcnt[2];
  __shared__ int s_anyfb;

  if (tid == 0) s_anyfb = 0;
  __syncthreads();

  unsigned long long mb = 0;
  int code = -1;
  bool act = false;
  if (tid < BITSZ) {
    code = v[b * BITSZ + tid];
    act = code >= 0;
    mb = __ballot(act);
    if ((tid & 63) == 0) s_wcnt[tid >> 6] = __popcll(mb);
  }
  __syncthreads();
  const int m = s_wcnt[0] + s_wcnt[1];
  if (tid < BITSZ && act) {
    const int lane = tid & 63;
    const int pos = ((tid >= 64) ? s_wcnt[0] : 0) +
                    __popcll(mb & ((1ull << lane) - 1ull));
    s_list[pos] = (code << 7) | tid;  // idx<<7 | t
    if (!(use_tab && code >= IBASE)) atomicOr(&s_anyfb, 1);
  }
  __syncthreads();

  // Stage active rows: 32 threads per row, 32 rows per pass.
  const int wrd = tid & 31;
  for (int jj = tid >> 5; jj < m; jj += 32) {
    const int e = s_list[jj];
    const int i = e >> 7, t = e & 127;
    if (use_tab && i >= IBASE)
      s_tab[(jj << 5) + wrd] = tab[((((t << 6) + (i - IBASE)) << 5)) + wrd];
  }
  __syncthreads();

  const int dw = tid >> 5, db = tid & 31;
  int acc = 0;
  if (s_anyfb == 0) {
#pragma unroll 4
    for (int jj = 0; jj < m; ++jj)
      acc += (s_tab[(jj << 5) + dw] >> db) & 1u;
  } else {
    for (int jj = 0; jj < m; ++jj) {
      const int e = s_list[jj];
      const int i = e >> 7, t = e & 127;
      if (use_tab && i >= IBASE) {
        acc += (s_tab[(jj << 5) + dw] >> db) & 1u;
      } else {
        const float u = runif(wk0, wk1,
            ((uint32_t)i << 17) + ((uint32_t)tid << 7) + (uint32_t)t);
        acc += (u <= w[i * D_OUT + tid]) ? 1 : 0;
      }
    }
  }
  out[b * D_OUT + tid] = (float)acc * (1.0f / (float)BITSZ);
}

struct TFKeys { uint32_t xk0, xk1, wk0, wk1, ck0, ck1; };

static TFKeys derive_keys() {
  TFKeys K;
  // partitionable split: key_i = both output words of E_{(0,42)}(0, i)
  uint32_t a0 = 0, a1 = 0; threefry2x32(0u, 42u, a0, a1); K.xk0 = a0; K.xk1 = a1;
  uint32_t b0 = 0, b1 = 1; threefry2x32(0u, 42u, b0, b1); K.wk0 = b0; K.wk1 = b1;
  uint32_t c0 = 0, c1 = 2; threefry2x32(0u, 42u, c0, c1); K.ck0 = c0; K.ck1 = c1;
  return K;
}

extern "C" void kernel_launch(void* const* d_in, const int* in_sizes, int n_in,
                              void* d_out, int out_size, void* d_ws, size_t ws_size,
                              hipStream_t stream) {
  const float* x = (const float*)d_in[0];
  const float* w = (const float*)d_in[1];
  if (n_in >= 2 && in_sizes[0] == D_IN * D_OUT && in_sizes[1] == BATCH * D_IN) {
    const float* tmp = x; x = w; w = tmp;
  }
  float* out = (float*)d_out;
  char* ws = (char*)d_ws;
  int* v = (int*)(ws + WS_V_OFF);
  uint32_t* mask = (uint32_t*)(ws + WS_MASK_OFF);
  uint32_t* tab = (uint32_t*)(ws + WS_TAB_OFF);

  const int use_tab = (ws_size >= WS_NEEDED) ? 1 : 0;
  const TFKeys K = derive_keys();

  if (use_tab)
    hipMemsetAsync(mask, 0, WS_MASK_BYTES, stream);

  hipLaunchKernelGGL(k_idx, dim3((BATCH * BITSZ) / 256), dim3(256), 0, stream,
                     x, v, mask, K.ck0, K.ck1, K.xk0, K.xk1, use_tab);
  if (use_tab)
    hipLaunchKernelGGL(k_tab, dim3(ICAP, BITSZ), dim3(256), 0, stream,
                       w, mask, tab, K.wk0, K.wk1);
  hipLaunchKernelGGL(k_acc, dim3(BATCH), dim3(D_OUT), 0, stream,
                     w, v, tab, out, K.wk0, K.wk1, use_tab);
}

// Round 3
// 24.806 us; speedup vs baseline: 6.7272x; 1.6000x over previous
//
#include <hip/hip_runtime.h>
#include <stdint.h>

#define BATCH 512
#define D_IN 1024
#define D_OUT 1024
#define BITSZ 128
#define N_STEPS (D_IN - 2)  // 1022

// Table covers idx in [IBASE, 1024). P(any idx < IBASE) ~ 65536 * 2^-64 ~ 4e-15;
// a direct-cipher fallback in k_acc keeps exactness for the impossible case.
#define IBASE 960
#define ICAP 64  // table rows per t column

// ws layout (no mask array anymore -> no memset needed)
#define WS_V_OFF 0u
#define WS_V_BYTES (BATCH * BITSZ * 4u)            // 262144
#define WS_TAB_OFF (WS_V_OFF + WS_V_BYTES)         // 262144
#define WS_TAB_BYTES (BITSZ * ICAP * 32u * 4u)     // 1048576
#define WS_NEEDED (WS_TAB_OFF + WS_TAB_BYTES)      // 1310720

__host__ __device__ __forceinline__ uint32_t rotl32(uint32_t x, uint32_t d) {
  return (x << d) | (x >> (32u - d));
}

// Threefry-2x32, 20 rounds, exactly as jax/_src/prng.py lowering.
__host__ __device__ __forceinline__ void threefry2x32(uint32_t k0, uint32_t k1,
                                                      uint32_t& x0, uint32_t& x1) {
  const uint32_t k2 = k0 ^ k1 ^ 0x1BD11BDAu;
  x0 += k0; x1 += k1;
#define TFR(r) { x0 += x1; x1 = rotl32(x1, (r)); x1 ^= x0; }
  TFR(13) TFR(15) TFR(26) TFR(6)
  x0 += k1; x1 += k2 + 1u;
  TFR(17) TFR(29) TFR(16) TFR(24)
  x0 += k2; x1 += k0 + 2u;
  TFR(13) TFR(15) TFR(26) TFR(6)
  x0 += k0; x1 += k1 + 3u;
  TFR(17) TFR(29) TFR(16) TFR(24)
  x0 += k1; x1 += k2 + 4u;
  TFR(13) TFR(15) TFR(26) TFR(6)
  x0 += k2; x1 += k0 + 5u;
#undef TFR
}

// jax_threefry_partitionable random_bits -> uniform [0,1):
// counts=(0,n), 20-round threefry, 32-bit fold, mantissa trick.
__device__ __forceinline__ float runif(uint32_t k0, uint32_t k1, uint32_t n) {
  uint32_t x0 = 0u, x1 = n;
  threefry2x32(k0, k1, x0, x1);
  const uint32_t b = x0 ^ x1;
  return __uint_as_float((b >> 9) | 0x3f800000u) - 1.0f;
}

// Kernel 1: one block per t (128 blocks, 1024 threads).
// Phase A (threads 0..511, thread==b): idx via top-down coin scan (geometric,
//   ~2 ciphers expected), x-bit cipher, v[b*128+t] = xbit ? idx : -1,
//   LDS presence bitmap for idx in [IBASE,1024).
// Phase B (all 1024 threads, thread==d): for each present row i, one cipher
//   per d; ballot-pack 1024 bits -> 32 words -> tab[t][i-IBASE][.].
__global__ void __launch_bounds__(1024) k_front(const float* __restrict__ x,
                                                int* __restrict__ v,
                                                uint32_t* __restrict__ tab,
                                                uint32_t ck0, uint32_t ck1,
                                                uint32_t xk0, uint32_t xk1,
                                                uint32_t wk0, uint32_t wk1,
                                                const float* __restrict__ w,
                                                int use_tab) {
  const int t = blockIdx.x;
  const int tid = threadIdx.x;

  __shared__ uint32_t s_bm[2];
  if (tid < 2) s_bm[tid] = 0u;
  __syncthreads();

  if (tid < BATCH) {
    const int b = tid;
    int idx = 0;
    for (int s = N_STEPS - 1; s >= 0; --s) {
      // coins linear index: s*(BATCH*BITSZ) + b*BITSZ + t
      const float u = runif(ck0, ck1,
          ((uint32_t)s << 16) + ((uint32_t)b << 7) + (uint32_t)t);
      if (u > 0.5f) { idx = s + 1; break; }
    }
    // x_bits linear index: b*(D_IN*BITSZ) + idx*BITSZ + t
    const float ux = runif(xk0, xk1,
        ((uint32_t)b << 17) + ((uint32_t)idx << 7) + (uint32_t)t);
    const int xb = (ux <= x[b * D_IN + idx]) ? 1 : 0;
    v[b * BITSZ + t] = xb ? idx : -1;
    if (xb && idx >= IBASE) {
      const int bp = idx - IBASE;
      atomicOr(&s_bm[bp >> 5], 1u << (bp & 31));
    }
  }
  __syncthreads();

  if (!use_tab) return;

  unsigned long long bm = (unsigned long long)s_bm[0] |
                          ((unsigned long long)s_bm[1] << 32);
  const int d = tid;
  const int lane = tid & 63;
  const int wv = tid >> 6;  // wave 0..15
  while (bm) {
    const int j = __builtin_ctzll(bm);
    bm &= bm - 1ull;
    const int i = IBASE + j;
    // w_bits linear index: i*(D_OUT*BITSZ) + d*BITSZ + t
    const float u = runif(wk0, wk1,
        ((uint32_t)i << 17) + ((uint32_t)d << 7) + (uint32_t)t);
    const unsigned long long mb = __ballot(u <= w[i * D_OUT + d]);
    uint32_t* row = tab + (((t << 6) + j) << 5);
    if (lane == 0)  row[wv * 2]     = (uint32_t)mb;
    if (lane == 32) row[wv * 2 + 1] = (uint32_t)(mb >> 32);
  }
}

// Kernel 2: per block b: compact active (t,idx) pairs, stage their packed rows
// into LDS (broadcast reads -> conflict-free), accumulate bits per d.
__global__ void __launch_bounds__(1024) k_acc(const float* __restrict__ w,
                                              const int* __restrict__ v,
                                              const uint32_t* __restrict__ tab,
                                              float* __restrict__ out,
                                              uint32_t wk0, uint32_t wk1,
                                              int use_tab) {
  const int b = blockIdx.x;
  const int tid = threadIdx.x;  // == d

  __shared__ uint32_t s_tab[BITSZ * 32];  // 16 KB
  __shared__ int s_list[BITSZ];
  __shared__ int s_wcnt[2];
  __shared__ int s_anyfb;

  if (tid == 0) s_anyfb = 0;
  __syncthreads();

  unsigned long long mb = 0;
  int code = -1;
  bool act = false;
  if (tid < BITSZ) {
    code = v[b * BITSZ + tid];
    act = code >= 0;
    mb = __ballot(act);
    if ((tid & 63) == 0) s_wcnt[tid >> 6] = __popcll(mb);
  }
  __syncthreads();
  const int m = s_wcnt[0] + s_wcnt[1];
  if (tid < BITSZ && act) {
    const int lane = tid & 63;
    const int pos = ((tid >= 64) ? s_wcnt[0] : 0) +
                    __popcll(mb & ((1ull << lane) - 1ull));
    s_list[pos] = (code << 7) | tid;  // idx<<7 | t
    if (!(use_tab && code >= IBASE)) atomicOr(&s_anyfb, 1);
  }
  __syncthreads();

  // Stage active rows: 32 threads per row, 32 rows per pass.
  const int wrd = tid & 31;
  for (int jj = tid >> 5; jj < m; jj += 32) {
    const int e = s_list[jj];
    const int i = e >> 7, t = e & 127;
    if (use_tab && i >= IBASE)
      s_tab[(jj << 5) + wrd] = tab[(((t << 6) + (i - IBASE)) << 5) + wrd];
  }
  __syncthreads();

  const int dw = tid >> 5, db = tid & 31;
  int acc = 0;
  if (s_anyfb == 0) {
#pragma unroll 4
    for (int jj = 0; jj < m; ++jj)
      acc += (s_tab[(jj << 5) + dw] >> db) & 1u;
  } else {
    for (int jj = 0; jj < m; ++jj) {
      const int e = s_list[jj];
      const int i = e >> 7, t = e & 127;
      if (use_tab && i >= IBASE) {
        acc += (s_tab[(jj << 5) + dw] >> db) & 1u;
      } else {
        const float u = runif(wk0, wk1,
            ((uint32_t)i << 17) + ((uint32_t)tid << 7) + (uint32_t)t);
        acc += (u <= w[i * D_OUT + tid]) ? 1 : 0;
      }
    }
  }
  out[b * D_OUT + tid] = (float)acc * (1.0f / (float)BITSZ);
}

struct TFKeys { uint32_t xk0, xk1, wk0, wk1, ck0, ck1; };

static TFKeys derive_keys() {
  TFKeys K;
  // partitionable split: key_i = both output words of E_{(0,42)}(0, i)
  uint32_t a0 = 0, a1 = 0; threefry2x32(0u, 42u, a0, a1); K.xk0 = a0; K.xk1 = a1;
  uint32_t b0 = 0, b1 = 1; threefry2x32(0u, 42u, b0, b1); K.wk0 = b0; K.wk1 = b1;
  uint32_t c0 = 0, c1 = 2; threefry2x32(0u, 42u, c0, c1); K.ck0 = c0; K.ck1 = c1;
  return K;
}

extern "C" void kernel_launch(void* const* d_in, const int* in_sizes, int n_in,
                              void* d_out, int out_size, void* d_ws, size_t ws_size,
                              hipStream_t stream) {
  const float* x = (const float*)d_in[0];
  const float* w = (const float*)d_in[1];
  if (n_in >= 2 && in_sizes[0] == D_IN * D_OUT && in_sizes[1] == BATCH * D_IN) {
    const float* tmp = x; x = w; w = tmp;
  }
  float* out = (float*)d_out;
  char* ws = (char*)d_ws;
  int* v = (int*)(ws + WS_V_OFF);
  uint32_t* tab = (uint32_t*)(ws + WS_TAB_OFF);

  const int use_tab = (ws_size >= WS_NEEDED) ? 1 : 0;
  const TFKeys K = derive_keys();

  hipLaunchKernelGGL(k_front, dim3(BITSZ), dim3(1024), 0, stream,
                     x, v, tab, K.ck0, K.ck1, K.xk0, K.xk1, K.wk0, K.wk1,
                     w, use_tab);
  hipLaunchKernelGGL(k_acc, dim3(BATCH), dim3(D_OUT), 0, stream,
                     w, v, tab, out, K.wk0, K.wk1, use_tab);
}

// Round 4
// 22.468 us; speedup vs baseline: 7.4273x; 1.1041x over previous
//
#include <hip/hip_runtime.h>
#include <stdint.h>

#define BATCH 512
#define D_IN 1024
#define D_OUT 1024
#define BITSZ 128
#define N_STEPS (D_IN - 2)  // 1022

// Table covers idx in [IBASE, 1024). P(any idx < IBASE) ~ 65536 * 2^-64 ~ 4e-15;
// a direct-cipher fallback in k_acc keeps exactness for the impossible case.
#define IBASE 960
#define ICAP 64  // table rows per t column

// ws layout (no global mask -> nothing needs zeroing)
#define WS_V_OFF 0u
#define WS_V_BYTES (BATCH * BITSZ * 4u)            // 262144
#define WS_TAB_OFF (WS_V_OFF + WS_V_BYTES)         // 262144
#define WS_TAB_BYTES (BITSZ * ICAP * 32u * 4u)     // 1048576
#define WS_NEEDED (WS_TAB_OFF + WS_TAB_BYTES)      // 1310720

// k_acc transposed staging: 32 d-word columns, padded stride.
// 132 words * 4B = 528B: 16B-aligned columns; bank(jj,wrd)=(4*wrd+jj)%32 -> 4-way max on writes.
#define MCAP 128
#define TSTRIDE 132

__host__ __device__ __forceinline__ uint32_t rotl32(uint32_t x, uint32_t d) {
  return (x << d) | (x >> (32u - d));
}

// Threefry-2x32, 20 rounds, exactly as jax/_src/prng.py lowering.
__host__ __device__ __forceinline__ void threefry2x32(uint32_t k0, uint32_t k1,
                                                      uint32_t& x0, uint32_t& x1) {
  const uint32_t k2 = k0 ^ k1 ^ 0x1BD11BDAu;
  x0 += k0; x1 += k1;
#define TFR(r) { x0 += x1; x1 = rotl32(x1, (r)); x1 ^= x0; }
  TFR(13) TFR(15) TFR(26) TFR(6)
  x0 += k1; x1 += k2 + 1u;
  TFR(17) TFR(29) TFR(16) TFR(24)
  x0 += k2; x1 += k0 + 2u;
  TFR(13) TFR(15) TFR(26) TFR(6)
  x0 += k0; x1 += k1 + 3u;
  TFR(17) TFR(29) TFR(16) TFR(24)
  x0 += k1; x1 += k2 + 4u;
  TFR(13) TFR(15) TFR(26) TFR(6)
  x0 += k2; x1 += k0 + 5u;
#undef TFR
}

// jax_threefry_partitionable random_bits -> uniform [0,1):
// counts=(0,n), 20-round threefry, 32-bit fold, mantissa trick.
__device__ __forceinline__ float runif(uint32_t k0, uint32_t k1, uint32_t n) {
  uint32_t x0 = 0u, x1 = n;
  threefry2x32(k0, k1, x0, x1);
  const uint32_t b = x0 ^ x1;
  return __uint_as_float((b >> 9) | 0x3f800000u) - 1.0f;
}

// Kernel 1: thread per (b,t). idx = max row with coin False, scanned top-down
// in speculative 4-wide batches (4 independent ciphers -> ILP hides the
// dependent threefry chain). Then x-bit; v[b*128+t] = xbit ? idx : -1.
__global__ void __launch_bounds__(256) k_idx(const float* __restrict__ x,
                                             int* __restrict__ v,
                                             uint32_t ck0, uint32_t ck1,
                                             uint32_t xk0, uint32_t xk1) {
  const int tid = blockIdx.x * 256 + threadIdx.x;  // 0..65535
  const int b = tid >> 7;
  const int t = tid & 127;

  int idx = 0;
  int s;
  for (s = N_STEPS - 1; s >= 3; s -= 4) {
    // coins linear index: s*(BATCH*BITSZ) + b*BITSZ + t == (s<<16) + tid
    const float u0 = runif(ck0, ck1, ((uint32_t)(s)     << 16) + (uint32_t)tid);
    const float u1 = runif(ck0, ck1, ((uint32_t)(s - 1) << 16) + (uint32_t)tid);
    const float u2 = runif(ck0, ck1, ((uint32_t)(s - 2) << 16) + (uint32_t)tid);
    const float u3 = runif(ck0, ck1, ((uint32_t)(s - 3) << 16) + (uint32_t)tid);
    if (u0 > 0.5f) { idx = s + 1; break; }
    if (u1 > 0.5f) { idx = s;     break; }
    if (u2 > 0.5f) { idx = s - 1; break; }
    if (u3 > 0.5f) { idx = s - 2; break; }
  }
  if (idx == 0 && s < 3) {  // tail: s = 1 and s = 0
    const float u0 = runif(ck0, ck1, (1u << 16) + (uint32_t)tid);
    const float u1 = runif(ck0, ck1, (uint32_t)tid);
    if (u0 > 0.5f)      idx = 2;
    else if (u1 > 0.5f) idx = 1;
  }

  // x_bits linear index: b*(D_IN*BITSZ) + idx*BITSZ + t
  const float ux = runif(xk0, xk1,
      ((uint32_t)b << 17) + ((uint32_t)idx << 7) + (uint32_t)t);
  const int xb = (ux <= x[b * D_IN + idx]) ? 1 : 0;
  v[tid] = xb ? idx : -1;
}

// Kernel 2: block = (t, d-quarter). Recompute per-t presence from v (u64
// shuffle OR-reduce), then build each present row's 256-bit d-quarter:
// one cipher per (row, d), ballot-packed into the global table.
__global__ void __launch_bounds__(256) k_tab(const float* __restrict__ w,
                                             const int* __restrict__ v,
                                             uint32_t* __restrict__ tab,
                                             uint32_t wk0, uint32_t wk1) {
  const int t = blockIdx.x >> 2;
  const int q = blockIdx.x & 3;
  const int tid = threadIdx.x;

  __shared__ uint32_t s_bm[2];
  if (tid < 2) s_bm[tid] = 0u;
  __syncthreads();

  unsigned long long m64 = 0;
  {
    const int v0 = v[tid * BITSZ + t];           // b = tid
    const int v1 = v[(tid + 256) * BITSZ + t];   // b = tid + 256
    if (v0 >= IBASE) m64 |= 1ull << (v0 - IBASE);
    if (v1 >= IBASE) m64 |= 1ull << (v1 - IBASE);
  }
  for (int off = 32; off; off >>= 1) m64 |= __shfl_down(m64, off);
  if ((tid & 63) == 0) {
    atomicOr(&s_bm[0], (uint32_t)m64);
    atomicOr(&s_bm[1], (uint32_t)(m64 >> 32));
  }
  __syncthreads();

  unsigned long long bm = (unsigned long long)s_bm[0] |
                          ((unsigned long long)s_bm[1] << 32);
  const int d = q * 256 + tid;
  const int lane = tid & 63;
  const int wbase = (d >> 5) & ~1;  // q*8 + wave*2
  while (bm) {
    const int j = __builtin_ctzll(bm);
    bm &= bm - 1ull;
    const int i = IBASE + j;
    // w_bits linear index: i*(D_OUT*BITSZ) + d*BITSZ + t
    const float u = runif(wk0, wk1,
        ((uint32_t)i << 17) + ((uint32_t)d << 7) + (uint32_t)t);
    const unsigned long long mb = __ballot(u <= w[i * D_OUT + d]);
    uint32_t* row = tab + (((t << 6) + j) << 5);
    if (lane == 0)  row[wbase]     = (uint32_t)mb;
    if (lane == 32) row[wbase + 1] = (uint32_t)(mb >> 32);
  }
}

// Kernel 3: block per b. Compact active (t,idx), stage rows TRANSPOSED into
// LDS ([32 dw][TSTRIDE]), accumulate with ds_read_b128 (4 rows/read,
// broadcast within half-wave, disjoint banks across halves).
__global__ void __launch_bounds__(1024) k_acc(const float* __restrict__ w,
                                              const int* __restrict__ v,
                                              const uint32_t* __restrict__ tab,
                                              float* __restrict__ out,
                                              uint32_t wk0, uint32_t wk1,
                                              int use_tab) {
  const int b = blockIdx.x;
  const int tid = threadIdx.x;  // == d

  __shared__ __align__(16) uint32_t s_tab2[32 * TSTRIDE];  // 16.9 KB
  __shared__ int s_list[BITSZ];
  __shared__ int s_wcnt[2];
  __shared__ int s_anyfb;

  if (tid == 0) s_anyfb = use_tab ? 0 : 1;
  __syncthreads();

  unsigned long long mb = 0;
  int code = -1;
  bool act = false;
  if (tid < BITSZ) {
    code = v[b * BITSZ + tid];
    act = code >= 0;
    mb = __ballot(act);
    if ((tid & 63) == 0) s_wcnt[tid >> 6] = __popcll(mb);
  }
  __syncthreads();
  const int m = s_wcnt[0] + s_wcnt[1];
  const int m4 = (m + 3) & ~3;
  if (tid < BITSZ && act) {
    const int lane = tid & 63;
    const int pos = ((tid >= 64) ? s_wcnt[0] : 0) +
                    __popcll(mb & ((1ull << lane) - 1ull));
    s_list[pos] = (code << 7) | tid;  // idx<<7 | t
    if (code < IBASE) atomicOr(&s_anyfb, 1);
  }
  __syncthreads();

  if (s_anyfb == 0) {
    // Transposed staging: column = d-word (wrd), row index jj along stride.
    const int wrd = tid & 31;
    for (int jj = tid >> 5; jj < m; jj += 32) {
      const int e = s_list[jj];
      const int i = e >> 7, t = e & 127;
      s_tab2[wrd * TSTRIDE + jj] = tab[(((t << 6) + (i - IBASE)) << 5) + wrd];
    }
    if (tid < 32)
      for (int jj = m; jj < m4; ++jj) s_tab2[tid * TSTRIDE + jj] = 0u;
    __syncthreads();

    const int dw = tid >> 5, db = tid & 31;
    const uint32_t* colp = &s_tab2[dw * TSTRIDE];
    int acc = 0;
    for (int k = 0; k < m4; k += 4) {
      const uint4 r = *(const uint4*)(colp + k);  // ds_read_b128: rows k..k+3
      acc += (r.x >> db) & 1u;
      acc += (r.y >> db) & 1u;
      acc += (r.z >> db) & 1u;
      acc += (r.w >> db) & 1u;
    }
    out[b * D_OUT + tid] = (float)acc * (1.0f / (float)BITSZ);
  } else {
    // Correctness fallback (idx < IBASE or tiny ws): direct ciphers.
    int acc = 0;
    for (int jj = 0; jj < m; ++jj) {
      const int e = s_list[jj];
      const int i = e >> 7, t = e & 127;
      const float u = runif(wk0, wk1,
          ((uint32_t)i << 17) + ((uint32_t)tid << 7) + (uint32_t)t);
      acc += (u <= w[i * D_OUT + tid]) ? 1 : 0;
    }
    out[b * D_OUT + tid] = (float)acc * (1.0f / (float)BITSZ);
  }
}

struct TFKeys { uint32_t xk0, xk1, wk0, wk1, ck0, ck1; };

static TFKeys derive_keys() {
  TFKeys K;
  // partitionable split: key_i = both output words of E_{(0,42)}(0, i)
  uint32_t a0 = 0, a1 = 0; threefry2x32(0u, 42u, a0, a1); K.xk0 = a0; K.xk1 = a1;
  uint32_t b0 = 0, b1 = 1; threefry2x32(0u, 42u, b0, b1); K.wk0 = b0; K.wk1 = b1;
  uint32_t c0 = 0, c1 = 2; threefry2x32(0u, 42u, c0, c1); K.ck0 = c0; K.ck1 = c1;
  return K;
}

extern "C" void kernel_launch(void* const* d_in, const int* in_sizes, int n_in,
                              void* d_out, int out_size, void* d_ws, size_t ws_size,
                              hipStream_t stream) {
  const float* x = (const float*)d_in[0];
  const float* w = (const float*)d_in[1];
  if (n_in >= 2 && in_sizes[0] == D_IN * D_OUT && in_sizes[1] == BATCH * D_IN) {
    const float* tmp = x; x = w; w = tmp;
  }
  float* out = (float*)d_out;
  char* ws = (char*)d_ws;
  int* v = (int*)(ws + WS_V_OFF);
  uint32_t* tab = (uint32_t*)(ws + WS_TAB_OFF);

  const int use_tab = (ws_size >= WS_NEEDED) ? 1 : 0;
  const TFKeys K = derive_keys();

  hipLaunchKernelGGL(k_idx, dim3((BATCH * BITSZ) / 256), dim3(256), 0, stream,
                     x, v, K.ck0, K.ck1, K.xk0, K.xk1);
  if (use_tab)
    hipLaunchKernelGGL(k_tab, dim3(BITSZ * 4), dim3(256), 0, stream,
                       w, v, tab, K.wk0, K.wk1);
  hipLaunchKernelGGL(k_acc, dim3(BATCH), dim3(D_OUT), 0, stream,
                     w, v, tab, out, K.wk0, K.wk1, use_tab);
}